// Round 12
// baseline (918.635 us; speedup 1.0000x reference)
//
#include <hip/hip_runtime.h>

#define TPB 256
#define NLB 64    // LSTM blocks
#define NCW 384   // conv worker blocks
#define NBLK 448

typedef float f32x4 __attribute__((ext_vector_type(4)));
typedef short bf16x8 __attribute__((ext_vector_type(8)));
typedef unsigned long long u64;

// ---------- helpers ----------
__device__ __forceinline__ float bf2f(unsigned short u) {
  union { unsigned int i; float f; } x; x.i = ((unsigned int)u) << 16; return x.f;
}
__device__ __forceinline__ unsigned short f2bf(float v) {
  union { float f; unsigned int i; } x; x.f = v;
  unsigned int r = (x.i + 0x7fffu + ((x.i >> 16) & 1u)) >> 16;
  return (unsigned short)r;
}
__device__ __forceinline__ float sigf(float x) { return 1.f / (1.f + __expf(-x)); }
__device__ __forceinline__ bf16x8 lda_bf8(const unsigned short* p) {
  union { uint4 u; bf16x8 v; } t; t.u = *(const uint4*)p; return t.v;
}
__device__ __forceinline__ bf16x8 frag_of(const unsigned int* w) {
  union { unsigned int u[4]; bf16x8 v; } t;
  t.u[0] = w[0]; t.u[1] = w[1]; t.u[2] = w[2]; t.u[3] = w[3]; return t.v;
}
__device__ __forceinline__ uint4 bnpack(uint4 v, const float* sst) {
  unsigned int d[4] = {v.x, v.y, v.z, v.w};
  uint4 o; unsigned int* op = (unsigned int*)&o;
#pragma unroll
  for (int t = 0; t < 4; ++t) {
    float a = fmaxf(fmaf(bf2f((unsigned short)(d[t] & 0xffff)), sst[4 * t], sst[4 * t + 1]), 0.f);
    float b = fmaxf(fmaf(bf2f((unsigned short)(d[t] >> 16)), sst[4 * t + 2], sst[4 * t + 3]), 0.f);
    op[t] = (unsigned int)f2bf(a) | ((unsigned int)f2bf(b) << 16);
  }
  return o;
}

// ---------- device barrier among the NCW conv workers ----------
__device__ __forceinline__ void cbar(int* bar, int idx) {
  __syncthreads();
  if (threadIdx.x == 0) {
    __hip_atomic_fetch_add(&bar[idx], 1, __ATOMIC_RELEASE, __HIP_MEMORY_SCOPE_AGENT);
    while (__hip_atomic_load(&bar[idx], __ATOMIC_RELAXED, __HIP_MEMORY_SCOPE_AGENT) < NCW)
      __builtin_amdgcn_s_sleep(8);
    (void)__hip_atomic_load(&bar[idx], __ATOMIC_ACQUIRE, __HIP_MEMORY_SCOPE_AGENT);
  }
  __syncthreads();
}

// ---------- BN final reduce (one channel per calling block) ----------
__device__ void ssr(const float* part, const float* gamma, const float* beta,
                    float* ss, float inv_count, int c, float* red) {
  const int tid = threadIdx.x;
  float s = 0.f, q = 0.f;
  for (int g = tid; g < NCW; g += TPB) {
    s += part[(size_t)g * 256 + c * 2];
    q += part[(size_t)g * 256 + c * 2 + 1];
  }
  red[tid] = s; red[256 + tid] = q;
  __syncthreads();
  for (int off = TPB / 2; off > 0; off >>= 1) {
    if (tid < off) { red[tid] += red[tid + off]; red[256 + tid] += red[256 + tid + off]; }
    __syncthreads();
  }
  if (tid == 0) {
    float mean = red[0] * inv_count;
    float var  = red[256] * inv_count - mean * mean;
    float rstd = rsqrtf(var + 1e-5f);
    float scl  = gamma[c] * rstd;
    ss[2 * c] = scl;
    ss[2 * c + 1] = beta[c] - mean * scl;
  }
}

// ---------- one conv_tap tile (channel-last, tap-shifted MFMA, stats into racc) ----------
template<int CIN, int CB, int NS, int HIN, int HOUT>
__device__ void ctap_tile(
    const unsigned short* __restrict__ inb, const unsigned short* __restrict__ wT,
    const float* __restrict__ bias, unsigned short* __restrict__ out,
    int t, unsigned short* patch, unsigned short* Bsm, const float* ssl,
    float* swsum, float* swsq, float* racc_s, float* racc_q) {
  constexpr int K = CIN * 9;
  constexpr int K8 = K / 8;
  constexpr int NCH = (K8 + 3) / 4;
  constexpr int KPAD = NCH * 32;
  constexpr int BS = KPAD + 8;
  constexpr int CINP = CIN + 8;
  constexpr int ICG_SH = (CIN == 16) ? 1 : (CIN == 32) ? 2 : 3;
  constexpr int TPR = HOUT / 8;
  constexpr int TILES = TPR * TPR;
  constexpr int NT = CB / 16;
  constexpr int COUT_TOT = CB * NS;

  const int tid = threadIdx.x;
  const int n = t / (TILES * NS);
  const int rem = t % (TILES * NS);
  const int tile = rem / NS;
  const int split = rem % NS;
  const int TR0 = (tile / TPR) * 8, TC0 = (tile % TPR) * 8;
  const int oc0 = split * CB;

  __syncthreads();   // protect patch/Bsm/swsum from previous tile
  // ---- patch stage ----
  for (int e = tid; e < 289 * (CIN / 8); e += TPB) {
    int icg = e % (CIN / 8), pix = e / (CIN / 8);
    int row = pix / 17, col = pix % 17;
    int ir = 2 * TR0 - 1 + row, jc = 2 * TC0 - 1 + col;
    uint4 o = {0u, 0u, 0u, 0u};
    if ((unsigned)ir < (unsigned)HIN && (unsigned)jc < (unsigned)HIN) {
      uint4 v = *(const uint4*)&inb[(((size_t)n * HIN + ir) * HIN + jc) * CIN + icg * 8];
      unsigned int d[4] = {v.x, v.y, v.z, v.w};
      unsigned int* op = (unsigned int*)&o;
#pragma unroll
      for (int tt = 0; tt < 4; ++tt) {
        int c = icg * 8 + 2 * tt;
        float a = fmaxf(fmaf(bf2f((unsigned short)(d[tt] & 0xffff)), ssl[2 * c], ssl[2 * c + 1]), 0.f);
        float b = fmaxf(fmaf(bf2f((unsigned short)(d[tt] >> 16)), ssl[2 * c + 2], ssl[2 * c + 3]), 0.f);
        op[tt] = (unsigned int)f2bf(a) | ((unsigned int)f2bf(b) << 16);
      }
    }
    *(uint4*)&patch[pix * CINP + icg * 8] = o;
  }
  if (NS > 1) {   // per-tile B stage (split varies)
    for (int e = tid; e < CB * (KPAD / 8); e += TPB) {
      int oc = e / (KPAD / 8), k8i = e % (KPAD / 8);
      uint4 v = {0u, 0u, 0u, 0u};
      if (k8i * 8 < K) v = *(const uint4*)&wT[(size_t)(oc0 + oc) * K + k8i * 8];
      *(uint4*)&Bsm[oc * BS + k8i * 8] = v;
    }
  }
  __syncthreads();

  const int wave = tid >> 6, lane = tid & 63;
  const int fr = lane & 15, kg = lane >> 4;
  const int p = wave * 16 + fr;
  const int pr = p >> 3, pc = p & 7;
  f32x4 acc[NT];
#pragma unroll
  for (int j = 0; j < NT; ++j) acc[j] = {0.f, 0.f, 0.f, 0.f};

#pragma unroll
  for (int ch = 0; ch < NCH; ++ch) {
    int k8 = ch * 4 + kg;
    int tap = k8 >> ICG_SH, icg = k8 & ((1 << ICG_SH) - 1);
    int ki = (tap * 11) >> 5;
    int kj = tap - 3 * ki;
    int addr = ((2 * pr + ki) * 17 + (2 * pc + kj)) * CINP + icg * 8;
    if (tap >= 9) addr = 0;
    bf16x8 af = lda_bf8(&patch[addr]);
#pragma unroll
    for (int j = 0; j < NT; ++j) {
      bf16x8 bfr = lda_bf8(&Bsm[(j * 16 + fr) * BS + ch * 32 + kg * 8]);
      acc[j] = __builtin_amdgcn_mfma_f32_16x16x32_bf16(af, bfr, acc[j], 0, 0, 0);
    }
  }
  const int rg = lane >> 4;
#pragma unroll
  for (int j = 0; j < NT; ++j) {
    int oc = oc0 + j * 16 + fr;
    float bb = bias[oc];
    float s1 = 0.f, q1 = 0.f;
#pragma unroll
    for (int r = 0; r < 4; ++r) {
      int pp = wave * 16 + rg * 4 + r;
      int orow = TR0 + (pp >> 3), ocol = TC0 + (pp & 7);
      float v = acc[j][r] + bb;
      s1 += v; q1 = fmaf(v, v, q1);
      out[(((size_t)n * HOUT + orow) * HOUT + ocol) * COUT_TOT + oc] = f2bf(v);
    }
    s1 += __shfl_xor(s1, 16); q1 += __shfl_xor(q1, 16);
    s1 += __shfl_xor(s1, 32); q1 += __shfl_xor(q1, 32);
    if (lane < 16) { swsum[wave * CB + j * 16 + fr] = s1; swsq[wave * CB + j * 16 + fr] = q1; }
  }
  __syncthreads();
  if (tid < CB) {
    float s = swsum[tid] + swsum[CB + tid] + swsum[2 * CB + tid] + swsum[3 * CB + tid];
    float q = swsq[tid] + swsq[CB + tid] + swsq[2 * CB + tid] + swsq[3 * CB + tid];
    racc_s[oc0 + tid] += s; racc_q[oc0 + tid] += q;
  }
}

// ---------- generic 64x64 MFMA GEMM tile (fp32 I/O, bf16 compute) ----------
__device__ void dev_gemm64(const float* __restrict__ A, const float* __restrict__ W,
    const float* __restrict__ bias, float* __restrict__ out,
    int N, int K, int relu, int ldo, int coff, int bm, int bn, char* sm) {
  unsigned short* As = (unsigned short*)sm;
  unsigned short* Bs = (unsigned short*)(sm + 5120);
  const int tid = threadIdx.x, lane = tid & 63, wave = tid >> 6;
  const int wr = (wave >> 1) * 32, wc = (wave & 1) * 32;
  const int fr = lane & 15, kg = lane >> 4;
  const int sr = tid >> 2, sc = (tid & 3) * 8;
  f32x4 a00 = {0.f, 0.f, 0.f, 0.f}, a01 = a00, a10 = a00, a11 = a00;
  int nch = (K + 31) >> 5;
  for (int ch = 0; ch < nch; ++ch) {
    int kb = ch * 32;
    __syncthreads();
    {
      unsigned short tmp[8];
#pragma unroll
      for (int j = 0; j < 8; ++j) {
        int k = kb + sc + j;
        tmp[j] = (k < K) ? f2bf(A[(size_t)(bm + sr) * K + k]) : (unsigned short)0;
      }
      *(uint4*)&As[sr * 40 + sc] = *(const uint4*)tmp;
      int wrow = bn + sr;
#pragma unroll
      for (int j = 0; j < 8; ++j) {
        int k = kb + sc + j;
        tmp[j] = (wrow < N && k < K) ? f2bf(W[(size_t)wrow * K + k]) : (unsigned short)0;
      }
      *(uint4*)&Bs[sr * 40 + sc] = *(const uint4*)tmp;
    }
    __syncthreads();
    bf16x8 af0 = lda_bf8(&As[(wr + fr) * 40 + kg * 8]);
    bf16x8 af1 = lda_bf8(&As[(wr + 16 + fr) * 40 + kg * 8]);
    bf16x8 bf0 = lda_bf8(&Bs[(wc + fr) * 40 + kg * 8]);
    bf16x8 bf1 = lda_bf8(&Bs[(wc + 16 + fr) * 40 + kg * 8]);
    a00 = __builtin_amdgcn_mfma_f32_16x16x32_bf16(af0, bf0, a00, 0, 0, 0);
    a01 = __builtin_amdgcn_mfma_f32_16x16x32_bf16(af0, bf1, a01, 0, 0, 0);
    a10 = __builtin_amdgcn_mfma_f32_16x16x32_bf16(af1, bf0, a10, 0, 0, 0);
    a11 = __builtin_amdgcn_mfma_f32_16x16x32_bf16(af1, bf1, a11, 0, 0, 0);
  }
  __syncthreads();
  const int rg = lane >> 4;
  int n0 = bn + wc + fr, n1 = n0 + 16;
  float bi0 = (n0 < N) ? bias[n0] : 0.f;
  float bi1 = (n1 < N) ? bias[n1] : 0.f;
#pragma unroll
  for (int r = 0; r < 4; ++r) {
    int m0 = bm + wr + rg * 4 + r, m1 = m0 + 16;
    if (n0 < N) {
      float v = a00[r] + bi0; out[(size_t)m0 * ldo + coff + n0] = relu ? fmaxf(v, 0.f) : v;
      v = a10[r] + bi0;       out[(size_t)m1 * ldo + coff + n0] = relu ? fmaxf(v, 0.f) : v;
    }
    if (n1 < N) {
      float v = a01[r] + bi1; out[(size_t)m0 * ldo + coff + n1] = relu ? fmaxf(v, 0.f) : v;
      v = a11[r] + bi1;       out[(size_t)m1 * ldo + coff + n1] = relu ? fmaxf(v, 0.f) : v;
    }
  }
}

// ---------- fc1 64x64 tile (bf16 in, BN fused on A) ----------
__device__ void dev_fc1(const unsigned short* __restrict__ A, const unsigned short* __restrict__ W,
    const float* __restrict__ ss, const float* __restrict__ bias, float* __restrict__ out,
    int bm, int bn, char* sm) {
  unsigned short (*As)[64] = (unsigned short (*)[64])sm;
  unsigned short (*Bs)[64] = (unsigned short (*)[64])(sm + 8192);
  float* ssl = (float*)(sm + 16384);
  const int tid = threadIdx.x;
  const int lane = tid & 63, wave = tid >> 6;
  const int wr = (wave >> 1) * 32, wc = (wave & 1) * 32;
  f32x4 acc00 = {0.f, 0.f, 0.f, 0.f}, acc01 = acc00, acc10 = acc00, acc11 = acc00;
  const int r0 = tid >> 3, c0 = tid & 7;
  const int fr = lane & 15, kg = lane >> 4;
  for (int i = tid; i < 256; i += TPB) ssl[i] = ss[i];
  __syncthreads();
  for (int kt = 0; kt < 128; ++kt) {
    const int kb = kt * 64;
    uint4 av0 = *(const uint4*)&A[(size_t)(bm + r0) * 8192 + kb + c0 * 8];
    uint4 av1 = *(const uint4*)&A[(size_t)(bm + r0 + 32) * 8192 + kb + c0 * 8];
    uint4 bv0 = *(const uint4*)&W[(size_t)(bn + r0) * 8192 + kb + c0 * 8];
    uint4 bv1 = *(const uint4*)&W[(size_t)(bn + r0 + 32) * 8192 + kb + c0 * 8];
    const float* sst = &ssl[2 * ((kb + c0 * 8) & 127)];
    __syncthreads();
    av0 = bnpack(av0, sst);
    av1 = bnpack(av1, sst);
    *(uint4*)&As[r0][(c0 ^ (r0 & 7)) * 8] = av0;
    *(uint4*)&As[r0 + 32][(c0 ^ (r0 & 7)) * 8] = av1;
    *(uint4*)&Bs[r0][(c0 ^ (r0 & 7)) * 8] = bv0;
    *(uint4*)&Bs[r0 + 32][(c0 ^ (r0 & 7)) * 8] = bv1;
    __syncthreads();
#pragma unroll
    for (int ks = 0; ks < 2; ++ks) {
      int ch = ks * 4 + kg;
      int ra0 = wr + fr, ra1 = wr + 16 + fr;
      int rb0 = wc + fr, rb1 = wc + 16 + fr;
      bf16x8 a_0 = lda_bf8(&As[ra0][(ch ^ (ra0 & 7)) * 8]);
      bf16x8 a_1 = lda_bf8(&As[ra1][(ch ^ (ra1 & 7)) * 8]);
      bf16x8 b_0 = lda_bf8(&Bs[rb0][(ch ^ (rb0 & 7)) * 8]);
      bf16x8 b_1 = lda_bf8(&Bs[rb1][(ch ^ (rb1 & 7)) * 8]);
      acc00 = __builtin_amdgcn_mfma_f32_16x16x32_bf16(a_0, b_0, acc00, 0, 0, 0);
      acc01 = __builtin_amdgcn_mfma_f32_16x16x32_bf16(a_0, b_1, acc01, 0, 0, 0);
      acc10 = __builtin_amdgcn_mfma_f32_16x16x32_bf16(a_1, b_0, acc10, 0, 0, 0);
      acc11 = __builtin_amdgcn_mfma_f32_16x16x32_bf16(a_1, b_1, acc11, 0, 0, 0);
    }
  }
  __syncthreads();
  const int rg = lane >> 4;
  int n0 = bn + wc + fr, n1 = n0 + 16;
  float bi0 = bias[n0], bi1 = bias[n1];
#pragma unroll
  for (int r = 0; r < 4; ++r) {
    int m0 = bm + wr + rg * 4 + r, m1 = m0 + 16;
    out[m0 * 512 + n0] = fmaxf(acc00[r] + bi0, 0.f);
    out[m0 * 512 + n1] = fmaxf(acc01[r] + bi1, 0.f);
    out[m1 * 512 + n0] = fmaxf(acc10[r] + bi0, 0.f);
    out[m1 * 512 + n1] = fmaxf(acc11[r] + bi1, 0.f);
  }
}

// ---------- prep kernels (unchanged) ----------
__global__ __launch_bounds__(TPB) void prep_wt(
    const float* __restrict__ w1, const float* __restrict__ w2,
    const float* __restrict__ w3, const float* __restrict__ w4,
    unsigned short* __restrict__ wt1, unsigned short* __restrict__ wt2,
    unsigned short* __restrict__ wt3, unsigned short* __restrict__ wt4) {
  int i = blockIdx.x * TPB + threadIdx.x;
  if (i < 1536) {
    int oc = i / 96, k = i % 96;
    int tap = k >> 3, ic = k & 7;
    float v = (tap < 9 && ic < 3) ? w1[(oc * 3 + ic) * 9 + tap] : 0.f;
    wt1[i] = f2bf(v);
  } else if (i < 6144) {
    int j = i - 1536;
    int oc = j / 144, k = j % 144;
    wt2[j] = f2bf(w2[(oc * 16 + (k & 15)) * 9 + (k >> 4)]);
  } else if (i < 24576) {
    int j = i - 6144;
    int oc = j / 288, k = j % 288;
    wt3[j] = f2bf(w3[(oc * 32 + (k & 31)) * 9 + (k >> 5)]);
  } else if (i < 98304) {
    int j = i - 24576;
    int oc = j / 576, k = j % 576;
    wt4[j] = f2bf(w4[(oc * 64 + (k & 63)) * 9 + (k >> 6)]);
  }
}

__global__ __launch_bounds__(TPB) void permute_fw1(const float* __restrict__ in,
    unsigned short* __restrict__ out) {
  __shared__ unsigned short l[128 * 66];
  int n = blockIdx.x;
  for (int e = threadIdx.x; e < 8192; e += TPB) {
    int c = e >> 6, pix = e & 63;
    l[c * 66 + pix] = f2bf(in[(size_t)n * 8192 + e]);
  }
  __syncthreads();
  for (int e = threadIdx.x; e < 8192; e += TPB) {
    int pix = e >> 7, c = e & 127;
    out[(size_t)n * 8192 + e] = l[c * 66 + pix];
  }
}

// ================= THE MEGA KERNEL =================
__global__ __launch_bounds__(TPB, 2) void mega_kernel(
    const float* __restrict__ fmap, const float* __restrict__ cond,
    const float* __restrict__ iseq, const float* __restrict__ steps,
    const unsigned short* __restrict__ wt1, const unsigned short* __restrict__ wt2,
    const unsigned short* __restrict__ wt3, const unsigned short* __restrict__ wt4,
    const float* __restrict__ cb1, const float* __restrict__ cb2,
    const float* __restrict__ cb3, const float* __restrict__ cb4,
    const float* __restrict__ g1, const float* __restrict__ be1,
    const float* __restrict__ g2, const float* __restrict__ be2,
    const float* __restrict__ g3, const float* __restrict__ be3,
    const float* __restrict__ g4, const float* __restrict__ be4,
    const unsigned short* __restrict__ fw1bf, const float* __restrict__ fb1,
    const float* __restrict__ fw2, const float* __restrict__ fb2,
    const float* __restrict__ ew1, const float* __restrict__ eb1,
    const float* __restrict__ ew2, const float* __restrict__ eb2,
    const float* __restrict__ mw, const float* __restrict__ mb,
    const float* __restrict__ w_ih0, const float* __restrict__ w_hh0,
    const float* __restrict__ b_ih0, const float* __restrict__ b_hh0,
    const float* __restrict__ w_ih1, const float* __restrict__ w_hh1,
    const float* __restrict__ b_ih1, const float* __restrict__ b_hh1,
    const float* __restrict__ xw1, const float* __restrict__ xb1,
    const float* __restrict__ xw2, const float* __restrict__ xb2,
    const float* __restrict__ oww, const float* __restrict__ obb,
    unsigned short* __restrict__ y1bf, unsigned short* __restrict__ y2bf,
    unsigned short* __restrict__ y3bf, unsigned short* __restrict__ y4pre,
    float* __restrict__ part, float* ss1, float* ss2, float* ss3, float* ss4,
    float* __restrict__ f1, u64* __restrict__ h0x, u64* __restrict__ h1x,
    float* __restrict__ comb, float* __restrict__ cx1, float* __restrict__ cx2,
    float* __restrict__ d_out, int* __restrict__ bar) {
  __shared__ __align__(16) char sm[63488];
  __shared__ float racc_s[128], racc_q[128];
  const int tid = threadIdx.x;

  // ======================= LSTM role =======================
  if (blockIdx.x < NLB) {
    const int blkid = blockIdx.x;
    const int u0 = blkid * 4;
    float (*xz)[8][16] = (float (*)[8][16])sm;               // 32768
    char* reg2 = sm + 32768;                                  // 18944
    float* bias1s = (float*)(sm + 32768 + 18944);             // 64

    float (*embc)[8][32] = (float (*)[8][32])reg2;
    float* mwmb = (float*)(reg2 + 16384);
    unsigned short (*v0s)[264] = (unsigned short (*)[264])reg2;
    unsigned short (*w1h)[264] = (unsigned short (*)[264])(reg2 + 8448);
    float (*P0)[16]  = (float (*)[16])(reg2 + 16896);
    float (*P1a)[16] = (float (*)[16])(reg2 + 17408);
    float (*P1b)[16] = (float (*)[16])(reg2 + 17920);

    const int wv = tid >> 6, lane = tid & 63, fr = lane & 15, kg = lane >> 4;
    const int r = tid & 15, ks = tid >> 4;
    const int R  = (r >> 2) * 256 + u0 + (r & 3);
    const int Rf = (fr >> 2) * 256 + u0 + (fr & 3);

    unsigned int wfrag[8][4];
    {
      const float* wsrc = (wv == 0) ? w_hh0 : (wv == 1) ? w_ih1 : w_hh1;
#pragma unroll
      for (int ch = 0; ch < 8; ++ch)
#pragma unroll
        for (int d = 0; d < 4; ++d) {
          float lo = wsrc[(size_t)Rf * 256 + ch * 32 + kg * 8 + d * 2];
          float hi = wsrc[(size_t)Rf * 256 + ch * 32 + kg * 8 + d * 2 + 1];
          wfrag[ch][d] = (unsigned)f2bf(lo) | ((unsigned)f2bf(hi) << 16);
        }
    }
    float wtmp[32];
#pragma unroll
    for (int i = 0; i < 32; ++i) wtmp[i] = w_ih0[R * 32 + i];
    const float bias0r = b_ih0[R] + b_hh0[R];
    if (tid < 16) bias1s[tid] = b_ih1[R] + b_hh1[R];
    if (tid < 96) mwmb[tid] = (tid < 64) ? mw[tid] : mb[tid - 64];
    __syncthreads();

    for (int chunk = 0; chunk < 4; ++chunk) {
      if (tid < 128) {
        int pp = tid >> 3, b = tid & 7;
        int pg = chunk * 16 + pp;
        float s0 = iseq[(b * 64 + pg) * 2 + 0];
        float s1 = iseq[(b * 64 + pg) * 2 + 1];
        for (int k = 0; k < 32; ++k)
          embc[pp][b][k] = fmaxf(fmaf(mwmb[2 * k], s0, fmaf(mwmb[2 * k + 1], s1, mwmb[64 + k])), 0.f);
      }
      __syncthreads();
      {
        int pg = chunk * 16 + ks;
        for (int b = 0; b < 8; ++b) {
          float a = bias0r;
          const float* e = &embc[ks][b][0];
#pragma unroll
          for (int k = 0; k < 32; ++k) a = fmaf(wtmp[k], e[k], a);
          xz[pg][b][r] = a;
        }
      }
      __syncthreads();
    }

    for (int i = tid; i < 8 * 264; i += TPB) {
      v0s[8 + i / 264][i % 264] = 0;
      w1h[8 + i / 264][i % 264] = 0;
    }
    __syncthreads();

    float c0 = 0.f, c1 = 0.f;
    for (int p = 0; p <= 64; ++p) {
      if (tid < 128) {
        if (p >= 1) {
          const unsigned tag0 = (unsigned)p;
          const u64* s0p = &h0x[(size_t)(p - 1) * 1024 + tid * 8];
          u64 e[8];
          for (;;) {
            bool ok = true;
#pragma unroll
            for (int i = 0; i < 8; ++i) {
              e[i] = __hip_atomic_load(&s0p[i], __ATOMIC_RELAXED, __HIP_MEMORY_SCOPE_AGENT);
              ok &= ((unsigned)(e[i] >> 32) == tag0);
            }
            if (ok) break;
            __builtin_amdgcn_s_sleep(1);
          }
#pragma unroll
          for (int i = 0; i < 8; ++i) {
            int g = tid * 8 + i;
            int bb = (g >> 1) & 7, ub = (g >> 4) * 4 + (g & 1) * 2;
            *(unsigned int*)&v0s[bb][ub] = (unsigned int)e[i];
          }
        } else {
#pragma unroll
          for (int i = 0; i < 8; ++i) {
            int g = tid * 8 + i;
            int bb = (g >> 1) & 7, ub = (g >> 4) * 4 + (g & 1) * 2;
            *(unsigned int*)&v0s[bb][ub] = 0u;
          }
        }
      } else {
        int t2 = tid - 128;
        if (p >= 2) {
          const unsigned tag1 = (unsigned)(p - 1);
          const u64* s1p = &h1x[(size_t)(p - 2) * 1024 + t2 * 8];
          u64 e[8];
          for (;;) {
            bool ok = true;
#pragma unroll
            for (int i = 0; i < 8; ++i) {
              e[i] = __hip_atomic_load(&s1p[i], __ATOMIC_RELAXED, __HIP_MEMORY_SCOPE_AGENT);
              ok &= ((unsigned)(e[i] >> 32) == tag1);
            }
            if (ok) break;
            __builtin_amdgcn_s_sleep(1);
          }
#pragma unroll
          for (int i = 0; i < 8; ++i) {
            int g = t2 * 8 + i;
            int bb = (g >> 1) & 7, ub = (g >> 4) * 4 + (g & 1) * 2;
            *(unsigned int*)&w1h[bb][ub] = (unsigned int)e[i];
          }
        } else {
#pragma unroll
          for (int i = 0; i < 8; ++i) {
            int g = t2 * 8 + i;
            int bb = (g >> 1) & 7, ub = (g >> 4) * 4 + (g & 1) * 2;
            *(unsigned int*)&w1h[bb][ub] = 0u;
          }
        }
      }
      __syncthreads();

      if (wv == 0) {
        if (p < 64) {
          f32x4 acc = {0.f, 0.f, 0.f, 0.f};
#pragma unroll
          for (int ch = 0; ch < 8; ++ch) {
            bf16x8 af = lda_bf8(&v0s[fr][ch * 32 + kg * 8]);
            acc = __builtin_amdgcn_mfma_f32_16x16x32_bf16(af, frag_of(wfrag[ch]), acc, 0, 0, 0);
          }
#pragma unroll
          for (int j = 0; j < 4; ++j) {
            int bb2 = (lane >> 4) * 4 + j;
            if (bb2 < 8) P0[bb2][fr] = acc[j];
          }
        }
      } else if (wv == 1) {
        if (p >= 1) {
          f32x4 acc = {0.f, 0.f, 0.f, 0.f};
#pragma unroll
          for (int ch = 0; ch < 8; ++ch) {
            bf16x8 af = lda_bf8(&v0s[fr][ch * 32 + kg * 8]);
            acc = __builtin_amdgcn_mfma_f32_16x16x32_bf16(af, frag_of(wfrag[ch]), acc, 0, 0, 0);
          }
#pragma unroll
          for (int j = 0; j < 4; ++j) {
            int bb2 = (lane >> 4) * 4 + j;
            if (bb2 < 8) P1a[bb2][fr] = acc[j];
          }
        }
      } else if (wv == 2) {
        if (p >= 1) {
          f32x4 acc = {0.f, 0.f, 0.f, 0.f};
#pragma unroll
          for (int ch = 0; ch < 8; ++ch) {
            bf16x8 af = lda_bf8(&w1h[fr][ch * 32 + kg * 8]);
            acc = __builtin_amdgcn_mfma_f32_16x16x32_bf16(af, frag_of(wfrag[ch]), acc, 0, 0, 0);
          }
#pragma unroll
          for (int j = 0; j < 4; ++j) {
            int bb2 = (lane >> 4) * 4 + j;
            if (bb2 < 8) P1b[bb2][fr] = acc[j];
          }
        }
      }
      __syncthreads();

      if (tid < 32 && p < 64) {
        int b = tid >> 2, uu = tid & 3;
        float zi = P0[b][uu]      + xz[p][b][uu];
        float zf = P0[b][4 + uu]  + xz[p][b][4 + uu];
        float zg = P0[b][8 + uu]  + xz[p][b][8 + uu];
        float zo = P0[b][12 + uu] + xz[p][b][12 + uu];
        c0 = sigf(zf) * c0 + sigf(zi) * tanhf(zg);
        float h = sigf(zo) * tanhf(c0);
        float hp = __shfl_xor(h, 1);
        if (!(uu & 1)) {
          unsigned int d = (unsigned int)f2bf(h) | ((unsigned int)f2bf(hp) << 16);
          u64 v = ((u64)(unsigned)(p + 1) << 32) | d;
          __hip_atomic_store(&h0x[(size_t)p * 1024 + blkid * 16 + b * 2 + (uu >> 1)], v,
                             __ATOMIC_RELAXED, __HIP_MEMORY_SCOPE_AGENT);
        }
      } else if (tid >= 32 && tid < 64 && p >= 1) {
        int t2 = tid - 32, b = t2 >> 2, uu = t2 & 3;
        float zi = P1a[b][uu]      + P1b[b][uu]      + bias1s[uu];
        float zf = P1a[b][4 + uu]  + P1b[b][4 + uu]  + bias1s[4 + uu];
        float zg = P1a[b][8 + uu]  + P1b[b][8 + uu]  + bias1s[8 + uu];
        float zo = P1a[b][12 + uu] + P1b[b][12 + uu] + bias1s[12 + uu];
        c1 = sigf(zf) * c1 + sigf(zi) * tanhf(zg);
        float h = sigf(zo) * tanhf(c1);
        comb[(size_t)(b * 64 + (p - 1)) * 576 + u0 + uu] = h;
        float hp = __shfl_xor(h, 1);
        if (!(uu & 1)) {
          unsigned int d = (unsigned int)f2bf(h) | ((unsigned int)f2bf(hp) << 16);
          u64 v = ((u64)(unsigned)p << 32) | d;
          __hip_atomic_store(&h1x[(size_t)(p - 1) * 1024 + blkid * 16 + b * 2 + (uu >> 1)], v,
                             __ATOMIC_RELAXED, __HIP_MEMORY_SCOPE_AGENT);
        }
      }
    }
    __syncthreads();
    if (tid == 0)
      __hip_atomic_fetch_add(&bar[15], 1, __ATOMIC_RELEASE, __HIP_MEMORY_SCOPE_AGENT);
    return;
  }

  // ======================= conv-worker role =======================
  const int cid = blockIdx.x - NLB;

  // ---- P0: conv1 (crop gather, tap MFMA), stats fused ----
  {
    unsigned short (*patch)[132][8] = (unsigned short (*)[132][8])sm;  // 35904
    unsigned short (*Bsm)[104] = (unsigned short (*)[104])(sm + 35904);// 3328
    float* bs = (float*)(sm + 39232);                                   // 64
    float* swsum = (float*)(sm + 39296);                                // 256
    float* swsq  = (float*)(sm + 39552);                                // 256
    if (tid < 128) { racc_s[tid] = 0.f; racc_q[tid] = 0.f; }
    for (int e = tid; e < 1536; e += TPB) Bsm[e / 96][e % 96] = wt1[e];
    if (tid < 16) bs[tid] = cb1[tid];
    for (int e = tid; e < 17 * 132; e += TPB)
      *(uint4*)&patch[e / 132][e % 132][0] = uint4{0u, 0u, 0u, 0u};
    const int w = tid >> 6, lane = tid & 63, fr = lane & 15, kg = lane >> 4, rg = lane >> 4;
    for (int t = cid; t < 4096; t += NCW) {
      __syncthreads();
      const int n = t >> 3, R0 = (t & 7) << 3;
      const int yy = (int)iseq[n * 2], xx = (int)iseq[n * 2 + 1];
      const int bimg = n >> 6;
      for (int e = tid; e < 3 * 17 * 132; e += TPB) {
        int ic = e / 2244, rem = e % 2244, l = rem / 132, c = rem % 132;
        int i = 2 * R0 - 1 + l, j = c - 1;
        float v = 0.f;
        if ((unsigned)i < 128u && (unsigned)j < 128u) {
          int rr2 = yy + i - 64, cc = xx + j - 64;
          if ((unsigned)rr2 < 1024u && (unsigned)cc < 1024u)
            v = fmap[(((size_t)bimg * 3 + ic) << 20) + ((size_t)rr2 << 10) + cc];
        }
        patch[l][c][ic] = f2bf(v);
      }
      __syncthreads();
      f32x4 acc[8];
#pragma unroll
      for (int m = 0; m < 8; ++m) acc[m] = {0.f, 0.f, 0.f, 0.f};
#pragma unroll
      for (int ch = 0; ch < 3; ++ch) {
        int k8 = ch * 4 + kg;
        int ki = (k8 >= 9) ? 0 : ((k8 * 11) >> 5);
        int kj = (k8 >= 9) ? 0 : (k8 - 3 * ki);
        bf16x8 bfr = lda_bf8(&Bsm[fr][k8 * 8]);
#pragma unroll
        for (int m = 0; m < 8; ++m) {
          int p = w * 128 + m * 16 + fr;
          int pr = p >> 6, pc = p & 63;
          bf16x8 af = lda_bf8(&patch[2 * pr + ki][2 * pc + kj][0]);
          acc[m] = __builtin_amdgcn_mfma_f32_16x16x32_bf16(af, bfr, acc[m], 0, 0, 0);
        }
      }
      float bb = bs[fr];
      float sps = 0.f, spq = 0.f;
#pragma unroll
      for (int m = 0; m < 8; ++m) {
#pragma unroll
        for (int r = 0; r < 4; ++r) {
          int p = w * 128 + m * 16 + rg * 4 + r;
          int pr = p >> 6, pc = p & 63;
          float v = acc[m][r] + bb;
          sps += v; spq = fmaf(v, v, spq);
          y1bf[(((size_t)n * 64 + R0 + pr) * 64 + pc) * 16 + fr] = f2bf(v);
        }
      }
      sps += __shfl_xor(sps, 16); spq += __shfl_xor(spq, 16);
      sps += __shfl_xor(sps, 32); spq += __shfl_xor(spq, 32);
      if (lane < 16) { swsum[w * 16 + fr] = sps; swsq[w * 16 + fr] = spq; }
      __syncthreads();
      if (tid < 16) {
        racc_s[tid] += swsum[tid] + swsum[16 + tid] + swsum[32 + tid] + swsum[48 + tid];
        racc_q[tid] += swsq[tid] + swsq[16 + tid] + swsq[32 + tid] + swsq[48 + tid];
      }
    }
    __syncthreads();
    if (tid < 128) { part[(size_t)cid * 256 + tid * 2] = racc_s[tid]; part[(size_t)cid * 256 + tid * 2 + 1] = racc_q[tid]; }
  }
  cbar(bar, 0);
  if (cid < 16) ssr(part, g1, be1, ss1, 1.f / 2097152.f, cid, (float*)sm);
  cbar(bar, 1);

  // ---- P1: conv2 ----
  {
    constexpr int CIN = 16, CB = 32, KPAD = 160, BS = 168, K = 144;
    unsigned short* patch = (unsigned short*)sm;                   // 13872
    unsigned short* Bsm = (unsigned short*)(sm + 13872);           // 10752
    float* ssl = (float*)(sm + 24624);                             // 128
    float* swsum = ssl + CIN * 2;                                  // 512B
    float* swsq = swsum + 4 * CB;
    if (tid < 128) { racc_s[tid] = 0.f; racc_q[tid] = 0.f; }
    for (int i = tid; i < CIN * 2; i += TPB) ssl[i] = ss1[i];
    for (int e = tid; e < CB * (KPAD / 8); e += TPB) {
      int oc = e / (KPAD / 8), k8i = e % (KPAD / 8);
      uint4 v = {0u, 0u, 0u, 0u};
      if (k8i * 8 < K) v = *(const uint4*)&wt2[(size_t)oc * K + k8i * 8];
      *(uint4*)&Bsm[oc * BS + k8i * 8] = v;
    }
    for (int t = cid; t < 8192; t += NCW)
      ctap_tile<16, 32, 1, 64, 32>(y1bf, wt2, cb2, y2bf, t, patch, Bsm, ssl, swsum, swsq, racc_s, racc_q);
    __syncthreads();
    if (tid < 128) { part[(size_t)cid * 256 + tid * 2] = racc_s[tid]; part[(size_t)cid * 256 + tid * 2 + 1] = racc_q[tid]; }
  }
  cbar(bar, 2);
  if (cid < 32) ssr(part, g2, be2, ss2, 1.f / 524288.f, cid, (float*)sm);
  cbar(bar, 3);

  // ---- P2: conv3 ----
  {
    constexpr int CIN = 32, CB = 64, KPAD = 288, BS = 296, K = 288;
    unsigned short* patch = (unsigned short*)sm;                   // 23120
    unsigned short* Bsm = (unsigned short*)(sm + 23120);           // 37888
    float* ssl = (float*)(sm + 61008);                             // 256
    float* swsum = ssl + CIN * 2;                                  // 1024B
    float* swsq = swsum + 4 * CB;
    if (tid < 128) { racc_s[tid] = 0.f; racc_q[tid] = 0.f; }
    for (int i = tid; i < CIN * 2; i += TPB) ssl[i] = ss2[i];
    for (int e = tid; e < CB * (KPAD / 8); e += TPB) {
      int oc = e / (KPAD / 8), k8i = e % (KPAD / 8);
      uint4 v = *(const uint4*)&wt3[(size_t)oc * K + k8i * 8];
      *(uint4*)&Bsm[oc * BS + k8i * 8] = v;
    }
    for (int t = cid; t < 2048; t += NCW)
      ctap_tile<32, 64, 1, 32, 16>(y2bf, wt3, cb3, y3bf, t, patch, Bsm, ssl, swsum, swsq, racc_s, racc_q);
    __syncthreads();
    if (tid < 128) { part[(size_t)cid * 256 + tid * 2] = racc_s[tid]; part[(size_t)cid * 256 + tid * 2 + 1] = racc_q[tid]; }
  }
  cbar(bar, 4);
  if (cid < 64) ssr(part, g3, be3, ss3, 1.f / 131072.f, cid, (float*)sm);
  cbar(bar, 5);

  // ---- P3: conv4 (NSPLIT=8) ----
  {
    constexpr int CIN = 64;
    unsigned short* patch = (unsigned short*)sm;                   // 41616
    unsigned short* Bsm = (unsigned short*)(sm + 41616);           // 18688
    float* ssl = (float*)(sm + 60304);                             // 512
    float* swsum = ssl + CIN * 2;                                  // 256B
    float* swsq = swsum + 4 * 16;
    if (tid < 128) { racc_s[tid] = 0.f; racc_q[tid] = 0.f; }
    for (int i = tid; i < CIN * 2; i += TPB) ssl[i] = ss3[i];
    for (int t = cid; t < 4096; t += NCW)
      ctap_tile<64, 16, 8, 16, 8>(y3bf, wt4, cb4, y4pre, t, patch, Bsm, ssl, swsum, swsq, racc_s, racc_q);
    __syncthreads();
    if (tid < 128) { part[(size_t)cid * 256 + tid * 2] = racc_s[tid]; part[(size_t)cid * 256 + tid * 2 + 1] = racc_q[tid]; }
  }
  cbar(bar, 6);
  if (cid < 128) ssr(part, g4, be4, ss4, 1.f / 32768.f, cid, (float*)sm);
  cbar(bar, 7);

  // ---- P4: fc1 (64 tiles of 64x64) ----
  if (cid < 64) dev_fc1(y4pre, fw1bf, ss4, fb1, f1, (cid >> 3) * 64, (cid & 7) * 64, sm);
  cbar(bar, 8);

  // ---- P5: fw2 gemm -> comb[.,256:512) ; cond_enc -> comb[.,512:576) ----
  if (cid < 32) {
    dev_gemm64(f1, fw2, fb2, comb, 256, 512, 0, 576, 256, (cid >> 2) * 64, (cid & 3) * 64, sm);
  } else if (cid < 40) {
    float* w1s = (float*)sm;                    // 4096
    float* w2s = (float*)(sm + 4096);           // 33792
    float* hbuf = (float*)(sm + 37888);         // 16896
    const int row0 = (cid - 32) * 64;
    for (int e = tid; e < 128 * 8; e += TPB) {
      int k2 = e >> 3, tt = e & 7;
      w1s[k2 * 8 + tt] = (tt < 6) ? ew1[k2 * 6 + tt] : (tt == 6 ? eb1[k2] : 0.f);
    }
    for (int e = tid; e < 64 * 128; e += TPB) {
      int j = e >> 7, k2 = e & 127;
      w2s[j * 132 + k2] = ew2[j * 128 + k2];
    }
    __syncthreads();
    for (int half = 0; half < 2; ++half) {
      int row = tid >> 3, seg = tid & 7;
      int nrow = row0 + half * 32 + row;
      int b = nrow >> 6, s5 = nrow & 63;
      float e0 = cond[b * 5], e1 = cond[b * 5 + 1], e2 = cond[b * 5 + 2];
      float e3 = cond[b * 5 + 3], e4 = cond[b * 5 + 4];
      float e5 = steps[b * 64 + s5];
      for (int k2 = seg * 16; k2 < seg * 16 + 16; ++k2) {
        float a = fmaf(w1s[k2 * 8], e0, fmaf(w1s[k2 * 8 + 1], e1, fmaf(w1s[k2 * 8 + 2], e2,
                  fmaf(w1s[k2 * 8 + 3], e3, fmaf(w1s[k2 * 8 + 4], e4, fmaf(w1s[k2 * 8 + 5], e5, w1s[k2 * 8 + 6]))))));
        hbuf[row * 132 + k2] = fmaxf(a, 0.f);
      }
      __syncthreads();
      for (int j = seg * 8; j < seg * 8 + 8; ++j) {
        float a = eb2[j];
#pragma unroll 8
        for (int k2 = 0; k2 < 128; ++k2) a = fmaf(w2s[j * 132 + k2], hbuf[row * 132 + k2], a);
        comb[(size_t)nrow * 576 + 512 + j] = a;
      }
      __syncthreads();
    }
  }
  cbar(bar, 9);

  // ---- wait for LSTM (comb cols 0..255), then head ----
  if (tid == 0) {
    while (__hip_atomic_load(&bar[15], __ATOMIC_RELAXED, __HIP_MEMORY_SCOPE_AGENT) < NLB)
      __builtin_amdgcn_s_sleep(8);
    (void)__hip_atomic_load(&bar[15], __ATOMIC_ACQUIRE, __HIP_MEMORY_SCOPE_AGENT);
  }
  __syncthreads();
  if (cid < 16) dev_gemm64(comb, xw1, xb1, cx1, 128, 576, 1, 128, 0, (cid >> 1) * 64, (cid & 1) * 64, sm);
  cbar(bar, 10);
  if (cid < 8) dev_gemm64(cx1, xw2, xb2, cx2, 64, 128, 1, 64, 0, cid * 64, 0, sm);
  cbar(bar, 11);
  if (cid < 8) dev_gemm64(cx2, oww, obb, d_out, 2, 64, 0, 2, 0, cid * 64, 0, sm);
}

// ---------- launcher ----------
extern "C" void kernel_launch(void* const* d_in, const int* in_sizes, int n_in,
                              void* d_out, int out_size, void* d_ws, size_t ws_size,
                              hipStream_t stream) {
  const float* fmap  = (const float*)d_in[0];
  const float* cond  = (const float*)d_in[1];
  const float* iseq  = (const float*)d_in[2];
  const float* steps = (const float*)d_in[3];
  const float* cw1 = (const float*)d_in[4];  const float* cb1 = (const float*)d_in[5];
  const float* g1  = (const float*)d_in[6];  const float* be1 = (const float*)d_in[7];
  const float* cw2 = (const float*)d_in[8];  const float* cb2 = (const float*)d_in[9];
  const float* g2  = (const float*)d_in[10]; const float* be2 = (const float*)d_in[11];
  const float* cw3 = (const float*)d_in[12]; const float* cb3 = (const float*)d_in[13];
  const float* g3  = (const float*)d_in[14]; const float* be3 = (const float*)d_in[15];
  const float* cw4 = (const float*)d_in[16]; const float* cb4 = (const float*)d_in[17];
  const float* g4  = (const float*)d_in[18]; const float* be4 = (const float*)d_in[19];
  const float* fw1 = (const float*)d_in[20]; const float* fb1 = (const float*)d_in[21];
  const float* fw2 = (const float*)d_in[22]; const float* fb2 = (const float*)d_in[23];
  const float* ew1 = (const float*)d_in[24]; const float* eb1 = (const float*)d_in[25];
  const float* ew2 = (const float*)d_in[26]; const float* eb2 = (const float*)d_in[27];
  const float* mw  = (const float*)d_in[28]; const float* mb  = (const float*)d_in[29];
  const float* w_ih0 = (const float*)d_in[30]; const float* w_hh0 = (const float*)d_in[31];
  const float* b_ih0 = (const float*)d_in[32]; const float* b_hh0 = (const float*)d_in[33];
  const float* w_ih1 = (const float*)d_in[34]; const float* w_hh1 = (const float*)d_in[35];
  const float* b_ih1 = (const float*)d_in[36]; const float* b_hh1 = (const float*)d_in[37];
  const float* xw1 = (const float*)d_in[38]; const float* xb1 = (const float*)d_in[39];
  const float* xw2 = (const float*)d_in[40]; const float* xb2 = (const float*)d_in[41];
  const float* ow  = (const float*)d_in[42]; const float* ob  = (const float*)d_in[43];

  float* ws = (float*)d_ws;
  unsigned short* y1bf  = (unsigned short*)ws;
  unsigned short* y2bf  = (unsigned short*)(ws + 16777216);
  unsigned short* y3bf  = (unsigned short*)(ws + 25165824);
  unsigned short* y4pre = (unsigned short*)(ws + 29360128);
  unsigned short* fw1bf = (unsigned short*)(ws + 33554432);
  size_t base = 35651584;
  float* part  = ws + base; base += 524288;
  float* ss1   = ws + base; base += 32;
  float* ss2   = ws + base; base += 64;
  float* ss3   = ws + base; base += 128;
  float* ss4   = ws + base; base += 256;
  float* f1    = ws + base; base += 262144;
  u64*   h0x   = (u64*)(ws + base); base += 131072;
  u64*   h1x   = (u64*)(ws + base); base += 131072;
  int*   bar   = (int*)(ws + base); base += 64;
  float* comb  = ws + base; base += 294912;
  float* cx1   = ws + base; base += 65536;
  float* cx2   = ws + base; base += 32768;
  unsigned short* wt1 = (unsigned short*)(ws + base); base += 768;
  unsigned short* wt2 = (unsigned short*)(ws + base); base += 2304;
  unsigned short* wt3 = (unsigned short*)(ws + base); base += 9216;
  unsigned short* wt4 = (unsigned short*)(ws + base); base += 36864;

  // --- prep ---
  prep_wt<<<384, TPB, 0, stream>>>(cw1, cw2, cw3, cw4, wt1, wt2, wt3, wt4);
  permute_fw1<<<512, TPB, 0, stream>>>(fw1, fw1bf);
  // zero h0x + h1x + bar (contiguous)
  hipMemsetAsync(h0x, 0, 2 * 64 * 1024 * sizeof(u64) + 256, stream);

  // --- everything else in one persistent kernel ---
  mega_kernel<<<NBLK, TPB, 0, stream>>>(
      fmap, cond, iseq, steps,
      wt1, wt2, wt3, wt4, cb1, cb2, cb3, cb4,
      g1, be1, g2, be2, g3, be3, g4, be4,
      fw1bf, fb1, fw2, fb2, ew1, eb1, ew2, eb2, mw, mb,
      w_ih0, w_hh0, b_ih0, b_hh0, w_ih1, w_hh1, b_ih1, b_hh1,
      xw1, xb1, xw2, xb2, ow, ob,
      y1bf, y2bf, y3bf, y4pre,
      part, ss1, ss2, ss3, ss4,
      f1, h0x, h1x, comb, cx1, cx2,
      (float*)d_out, bar);
}

// Round 13
// 591.249 us; speedup vs baseline: 1.5537x; 1.5537x over previous
//
#include <hip/hip_runtime.h>

#define TPB 256
#define NLB 64   // LSTM blocks

typedef float f32x4 __attribute__((ext_vector_type(4)));
typedef short bf16x8 __attribute__((ext_vector_type(8)));
typedef unsigned long long u64;

// ---------- helpers ----------
__device__ __forceinline__ float bf2f(unsigned short u) {
  union { unsigned int i; float f; } x; x.i = ((unsigned int)u) << 16; return x.f;
}
__device__ __forceinline__ unsigned short f2bf(float v) {
  union { float f; unsigned int i; } x; x.f = v;
  unsigned int r = (x.i + 0x7fffu + ((x.i >> 16) & 1u)) >> 16;
  return (unsigned short)r;
}
__device__ __forceinline__ float sigf(float x) { return 1.f / (1.f + __expf(-x)); }
__device__ __forceinline__ bf16x8 lda_bf8(const unsigned short* p) {
  union { uint4 u; bf16x8 v; } t; t.u = *(const uint4*)p; return t.v;
}
__device__ __forceinline__ bf16x8 frag_of(const unsigned int* w) {
  union { unsigned int u[4]; bf16x8 v; } t;
  t.u[0] = w[0]; t.u[1] = w[1]; t.u[2] = w[2]; t.u[3] = w[3]; return t.v;
}
__device__ __forceinline__ uint4 bnpack(uint4 v, const float* sst) {
  unsigned int d[4] = {v.x, v.y, v.z, v.w};
  uint4 o; unsigned int* op = (unsigned int*)&o;
#pragma unroll
  for (int t = 0; t < 4; ++t) {
    float a = fmaxf(fmaf(bf2f((unsigned short)(d[t] & 0xffff)), sst[4 * t], sst[4 * t + 1]), 0.f);
    float b = fmaxf(fmaf(bf2f((unsigned short)(d[t] >> 16)), sst[4 * t + 2], sst[4 * t + 3]), 0.f);
    op[t] = (unsigned int)f2bf(a) | ((unsigned int)f2bf(b) << 16);
  }
  return o;
}

// ---------- LSTM segment (phases [p0,p1) of the r9-verified structure) ----------
__device__ void lstm_seg(int blkid, int p0, int p1, int first,
    const float* __restrict__ iseq, const float* __restrict__ mw, const float* __restrict__ mb,
    const float* __restrict__ w_ih0, const float* __restrict__ w_hh0,
    const float* __restrict__ b_ih0, const float* __restrict__ b_hh0,
    const float* __restrict__ w_ih1, const float* __restrict__ w_hh1,
    const float* __restrict__ b_ih1, const float* __restrict__ b_hh1,
    u64* __restrict__ h0x, u64* __restrict__ h1x,
    float* __restrict__ comb, float* __restrict__ xzg, float* __restrict__ cst,
    char* sm) {
  const int tid = threadIdx.x;
  const int u0 = blkid * 4;
  float (*xz)[8][16] = (float (*)[8][16])sm;              // 32768
  char* reg2 = sm + 32768;                                 // 18944
  float* bias1s = (float*)(sm + 51712);                    // 64

  float (*embc)[8][32] = (float (*)[8][32])reg2;
  float* mwmb = (float*)(reg2 + 16384);
  unsigned short (*v0s)[264] = (unsigned short (*)[264])reg2;
  unsigned short (*w1h)[264] = (unsigned short (*)[264])(reg2 + 8448);
  float (*P0)[16]  = (float (*)[16])(reg2 + 16896);
  float (*P1a)[16] = (float (*)[16])(reg2 + 17408);
  float (*P1b)[16] = (float (*)[16])(reg2 + 17920);

  const int wv = tid >> 6, lane = tid & 63, fr = lane & 15, kg = lane >> 4;
  const int r = tid & 15, ks = tid >> 4;
  const int R  = (r >> 2) * 256 + u0 + (r & 3);
  const int Rf = (fr >> 2) * 256 + u0 + (fr & 3);

  unsigned int wfrag[8][4];
  {
    const float* wsrc = (wv == 0) ? w_hh0 : (wv == 1) ? w_ih1 : w_hh1;
#pragma unroll
    for (int ch = 0; ch < 8; ++ch)
#pragma unroll
      for (int d = 0; d < 4; ++d) {
        float lo = wsrc[(size_t)Rf * 256 + ch * 32 + kg * 8 + d * 2];
        float hi = wsrc[(size_t)Rf * 256 + ch * 32 + kg * 8 + d * 2 + 1];
        wfrag[ch][d] = (unsigned)f2bf(lo) | ((unsigned)f2bf(hi) << 16);
      }
  }
  if (tid < 16) bias1s[tid] = b_ih1[R] + b_hh1[R];

  if (first) {
    float wtmp[32];
#pragma unroll
    for (int i = 0; i < 32; ++i) wtmp[i] = w_ih0[R * 32 + i];
    const float bias0r = b_ih0[R] + b_hh0[R];
    if (tid < 96) mwmb[tid] = (tid < 64) ? mw[tid] : mb[tid - 64];
    __syncthreads();
    for (int chunk = 0; chunk < 4; ++chunk) {
      if (tid < 128) {
        int pp = tid >> 3, b = tid & 7;
        int pg = chunk * 16 + pp;
        float s0 = iseq[(b * 64 + pg) * 2 + 0];
        float s1 = iseq[(b * 64 + pg) * 2 + 1];
        for (int k = 0; k < 32; ++k)
          embc[pp][b][k] = fmaxf(fmaf(mwmb[2 * k], s0, fmaf(mwmb[2 * k + 1], s1, mwmb[64 + k])), 0.f);
      }
      __syncthreads();
      {
        int pg = chunk * 16 + ks;
        for (int b = 0; b < 8; ++b) {
          float a = bias0r;
          const float* e = &embc[ks][b][0];
#pragma unroll
          for (int k = 0; k < 32; ++k) a = fmaf(wtmp[k], e[k], a);
          xz[pg][b][r] = a;
        }
      }
      __syncthreads();
    }
    for (int i = tid; i < 8192; i += TPB)
      xzg[(size_t)blkid * 8192 + i] = ((float*)xz)[i];
  } else {
    __syncthreads();
    for (int i = tid; i < 8192; i += TPB)
      ((float*)xz)[i] = xzg[(size_t)blkid * 8192 + i];
  }
  __syncthreads();

  for (int i = tid; i < 8 * 264; i += TPB) {
    v0s[8 + i / 264][i % 264] = 0;
    w1h[8 + i / 264][i % 264] = 0;
  }
  float c0 = 0.f, c1 = 0.f;
  if (!first) {
    if (tid < 32) c0 = cst[blkid * 64 + tid];
    else if (tid < 64) c1 = cst[blkid * 64 + tid];
  }
  __syncthreads();

  for (int p = p0; p < p1; ++p) {
    if (tid < 128) {
      if (p >= 1) {
        const unsigned tag0 = (unsigned)p;
        const u64* s0p = &h0x[(size_t)(p - 1) * 1024 + tid * 8];
        u64 e[8];
        for (;;) {
          bool ok = true;
#pragma unroll
          for (int i = 0; i < 8; ++i) {
            e[i] = __hip_atomic_load(&s0p[i], __ATOMIC_RELAXED, __HIP_MEMORY_SCOPE_AGENT);
            ok &= ((unsigned)(e[i] >> 32) == tag0);
          }
          if (ok) break;
          __builtin_amdgcn_s_sleep(1);
        }
#pragma unroll
        for (int i = 0; i < 8; ++i) {
          int g = tid * 8 + i;
          int bb = (g >> 1) & 7, ub = (g >> 4) * 4 + (g & 1) * 2;
          *(unsigned int*)&v0s[bb][ub] = (unsigned int)e[i];
        }
      } else {
#pragma unroll
        for (int i = 0; i < 8; ++i) {
          int g = tid * 8 + i;
          int bb = (g >> 1) & 7, ub = (g >> 4) * 4 + (g & 1) * 2;
          *(unsigned int*)&v0s[bb][ub] = 0u;
        }
      }
    } else {
      int t2 = tid - 128;
      if (p >= 2) {
        const unsigned tag1 = (unsigned)(p - 1);
        const u64* s1p = &h1x[(size_t)(p - 2) * 1024 + t2 * 8];
        u64 e[8];
        for (;;) {
          bool ok = true;
#pragma unroll
          for (int i = 0; i < 8; ++i) {
            e[i] = __hip_atomic_load(&s1p[i], __ATOMIC_RELAXED, __HIP_MEMORY_SCOPE_AGENT);
            ok &= ((unsigned)(e[i] >> 32) == tag1);
          }
          if (ok) break;
          __builtin_amdgcn_s_sleep(1);
        }
#pragma unroll
        for (int i = 0; i < 8; ++i) {
          int g = t2 * 8 + i;
          int bb = (g >> 1) & 7, ub = (g >> 4) * 4 + (g & 1) * 2;
          *(unsigned int*)&w1h[bb][ub] = (unsigned int)e[i];
        }
      } else {
#pragma unroll
        for (int i = 0; i < 8; ++i) {
          int g = t2 * 8 + i;
          int bb = (g >> 1) & 7, ub = (g >> 4) * 4 + (g & 1) * 2;
          *(unsigned int*)&w1h[bb][ub] = 0u;
        }
      }
    }
    __syncthreads();

    if (wv == 0) {
      if (p < 64) {
        f32x4 acc = {0.f, 0.f, 0.f, 0.f};
#pragma unroll
        for (int ch = 0; ch < 8; ++ch) {
          bf16x8 af = lda_bf8(&v0s[fr][ch * 32 + kg * 8]);
          acc = __builtin_amdgcn_mfma_f32_16x16x32_bf16(af, frag_of(wfrag[ch]), acc, 0, 0, 0);
        }
#pragma unroll
        for (int j = 0; j < 4; ++j) {
          int bb2 = (lane >> 4) * 4 + j;
          if (bb2 < 8) P0[bb2][fr] = acc[j];
        }
      }
    } else if (wv == 1) {
      if (p >= 1) {
        f32x4 acc = {0.f, 0.f, 0.f, 0.f};
#pragma unroll
        for (int ch = 0; ch < 8; ++ch) {
          bf16x8 af = lda_bf8(&v0s[fr][ch * 32 + kg * 8]);
          acc = __builtin_amdgcn_mfma_f32_16x16x32_bf16(af, frag_of(wfrag[ch]), acc, 0, 0, 0);
        }
#pragma unroll
        for (int j = 0; j < 4; ++j) {
          int bb2 = (lane >> 4) * 4 + j;
          if (bb2 < 8) P1a[bb2][fr] = acc[j];
        }
      }
    } else if (wv == 2) {
      if (p >= 1) {
        f32x4 acc = {0.f, 0.f, 0.f, 0.f};
#pragma unroll
        for (int ch = 0; ch < 8; ++ch) {
          bf16x8 af = lda_bf8(&w1h[fr][ch * 32 + kg * 8]);
          acc = __builtin_amdgcn_mfma_f32_16x16x32_bf16(af, frag_of(wfrag[ch]), acc, 0, 0, 0);
        }
#pragma unroll
        for (int j = 0; j < 4; ++j) {
          int bb2 = (lane >> 4) * 4 + j;
          if (bb2 < 8) P1b[bb2][fr] = acc[j];
        }
      }
    }
    __syncthreads();

    if (tid < 32 && p < 64) {
      int b = tid >> 2, uu = tid & 3;
      float zi = P0[b][uu]      + xz[p][b][uu];
      float zf = P0[b][4 + uu]  + xz[p][b][4 + uu];
      float zg = P0[b][8 + uu]  + xz[p][b][8 + uu];
      float zo = P0[b][12 + uu] + xz[p][b][12 + uu];
      c0 = sigf(zf) * c0 + sigf(zi) * tanhf(zg);
      float h = sigf(zo) * tanhf(c0);
      float hp = __shfl_xor(h, 1);
      if (!(uu & 1)) {
        unsigned int d = (unsigned int)f2bf(h) | ((unsigned int)f2bf(hp) << 16);
        u64 v = ((u64)(unsigned)(p + 1) << 32) | d;
        __hip_atomic_store(&h0x[(size_t)p * 1024 + blkid * 16 + b * 2 + (uu >> 1)], v,
                           __ATOMIC_RELAXED, __HIP_MEMORY_SCOPE_AGENT);
      }
    } else if (tid >= 32 && tid < 64 && p >= 1) {
      int t2 = tid - 32, b = t2 >> 2, uu = t2 & 3;
      float zi = P1a[b][uu]      + P1b[b][uu]      + bias1s[uu];
      float zf = P1a[b][4 + uu]  + P1b[b][4 + uu]  + bias1s[4 + uu];
      float zg = P1a[b][8 + uu]  + P1b[b][8 + uu]  + bias1s[8 + uu];
      float zo = P1a[b][12 + uu] + P1b[b][12 + uu] + bias1s[12 + uu];
      c1 = sigf(zf) * c1 + sigf(zi) * tanhf(zg);
      float h = sigf(zo) * tanhf(c1);
      comb[(size_t)(b * 64 + (p - 1)) * 576 + u0 + uu] = h;
      float hp = __shfl_xor(h, 1);
      if (!(uu & 1)) {
        unsigned int d = (unsigned int)f2bf(h) | ((unsigned int)f2bf(hp) << 16);
        u64 v = ((u64)(unsigned)p << 32) | d;
        __hip_atomic_store(&h1x[(size_t)(p - 1) * 1024 + blkid * 16 + b * 2 + (uu >> 1)], v,
                           __ATOMIC_RELAXED, __HIP_MEMORY_SCOPE_AGENT);
      }
    }
  }

  if (tid < 32) cst[blkid * 64 + tid] = c0;
  else if (tid < 64) cst[blkid * 64 + tid] = c1;
}

#define LSTM_ARGS const float* __restrict__ iseq_l, const float* __restrict__ mw, const float* __restrict__ mb, \
    const float* __restrict__ w_ih0, const float* __restrict__ w_hh0, \
    const float* __restrict__ b_ih0, const float* __restrict__ b_hh0, \
    const float* __restrict__ w_ih1, const float* __restrict__ w_hh1, \
    const float* __restrict__ b_ih1, const float* __restrict__ b_hh1, \
    u64* __restrict__ h0x, u64* __restrict__ h1x, float* __restrict__ comb, \
    float* __restrict__ xzg, float* __restrict__ cst, int p0, int p1, int first
#define LSTM_PASS(blk) lstm_seg(blk, p0, p1, first, iseq_l, mw, mb, w_ih0, w_hh0, b_ih0, b_hh0, \
    w_ih1, w_hh1, b_ih1, b_hh1, h0x, h1x, comb, xzg, cst, sm)

// ================= k_conv1: crop conv (+LSTM seg 0) =================
__global__ __launch_bounds__(TPB, 2) void k_conv1(
    const float* __restrict__ fmap, const float* __restrict__ iseq,
    const unsigned short* __restrict__ wT, const float* __restrict__ bias,
    unsigned short* __restrict__ out, float* __restrict__ part, LSTM_ARGS) {
  __shared__ __align__(16) char sm[52288];
  const int tid = threadIdx.x;
  if (blockIdx.x < NLB) { LSTM_PASS(blockIdx.x); return; }
  const int bidc = blockIdx.x - NLB;
  unsigned short (*patch)[132][8] = (unsigned short (*)[132][8])sm;   // 35904
  unsigned short (*Bsm)[104] = (unsigned short (*)[104])(sm + 35904); // 3328
  float* bs = (float*)(sm + 39232);
  float* swsum = (float*)(sm + 39296);
  float* swsq  = (float*)(sm + 39552);

  const int n = bidc >> 3, R0 = (bidc & 7) << 3;
  const int y = (int)iseq[n * 2], x = (int)iseq[n * 2 + 1];
  const int bimg = n >> 6;

  for (int e = tid; e < 1536; e += TPB) Bsm[e / 96][e % 96] = wT[e];
  if (tid < 16) bs[tid] = bias[tid];
  for (int e = tid; e < 17 * 132; e += TPB)
    *(uint4*)&patch[e / 132][e % 132][0] = uint4{0u, 0u, 0u, 0u};
  __syncthreads();
  for (int e = tid; e < 3 * 17 * 132; e += TPB) {
    int ic = e / 2244, rem = e % 2244, l = rem / 132, c = rem % 132;
    int i = 2 * R0 - 1 + l, j = c - 1;
    float v = 0.f;
    if ((unsigned)i < 128u && (unsigned)j < 128u) {
      int r = y + i - 64, cc = x + j - 64;
      if ((unsigned)r < 1024u && (unsigned)cc < 1024u)
        v = fmap[(((size_t)bimg * 3 + ic) << 20) + ((size_t)r << 10) + cc];
    }
    patch[l][c][ic] = f2bf(v);
  }
  __syncthreads();

  const int w = tid >> 6, lane = tid & 63, fr = lane & 15, kg = lane >> 4;
  f32x4 acc[8];
#pragma unroll
  for (int m = 0; m < 8; ++m) acc[m] = {0.f, 0.f, 0.f, 0.f};
#pragma unroll
  for (int ch = 0; ch < 3; ++ch) {
    int k8 = ch * 4 + kg;
    int ki = (k8 >= 9) ? 0 : ((k8 * 11) >> 5);
    int kj = (k8 >= 9) ? 0 : (k8 - 3 * ki);
    bf16x8 bfr = lda_bf8(&Bsm[fr][k8 * 8]);
#pragma unroll
    for (int m = 0; m < 8; ++m) {
      int p = w * 128 + m * 16 + fr;
      int pr = p >> 6, pc = p & 63;
      bf16x8 af = lda_bf8(&patch[2 * pr + ki][2 * pc + kj][0]);
      acc[m] = __builtin_amdgcn_mfma_f32_16x16x32_bf16(af, bfr, acc[m], 0, 0, 0);
    }
  }
  const int rg = lane >> 4;
  float bb = bs[fr];
  float sps = 0.f, spq = 0.f;
#pragma unroll
  for (int m = 0; m < 8; ++m) {
#pragma unroll
    for (int r = 0; r < 4; ++r) {
      int p = w * 128 + m * 16 + rg * 4 + r;
      int pr = p >> 6, pc = p & 63;
      float v = acc[m][r] + bb;
      sps += v; spq = fmaf(v, v, spq);
      out[(((size_t)n * 64 + R0 + pr) * 64 + pc) * 16 + fr] = f2bf(v);
    }
  }
  sps += __shfl_xor(sps, 16); spq += __shfl_xor(spq, 16);
  sps += __shfl_xor(sps, 32); spq += __shfl_xor(spq, 32);
  if (lane < 16) { swsum[w * 16 + fr] = sps; swsq[w * 16 + fr] = spq; }
  __syncthreads();
  if (tid < 16) {
    float s = swsum[tid] + swsum[16 + tid] + swsum[32 + tid] + swsum[48 + tid];
    float q = swsq[tid] + swsq[16 + tid] + swsq[32 + tid] + swsq[48 + tid];
    part[(size_t)bidc * 32 + tid * 2] = s;
    part[(size_t)bidc * 32 + tid * 2 + 1] = q;
  }
}

// ================= k_conv: tap-shifted MFMA conv (+LSTM seg) =================
template<int CIN, int CB, int NS, int HIN, int HOUT>
__global__ __launch_bounds__(TPB, 2) void k_conv(
    const unsigned short* __restrict__ inb, const float* __restrict__ ssx,
    const unsigned short* __restrict__ wT, const float* __restrict__ bias,
    unsigned short* __restrict__ out, float* __restrict__ part, LSTM_ARGS) {
  constexpr int K = CIN * 9;
  constexpr int K8 = K / 8;
  constexpr int NCH = (K8 + 3) / 4;
  constexpr int KPAD = NCH * 32;
  constexpr int BS = KPAD + 8;
  constexpr int CINP = CIN + 8;
  constexpr int ICG_SH = (CIN == 16) ? 1 : (CIN == 32) ? 2 : 3;
  constexpr int TPR = HOUT / 8;
  constexpr int NT = CB / 16;
  constexpr int COUT_TOT = CB * NS;
  constexpr int PB = 289 * CINP * 2;
  constexpr int BB = CB * BS * 2;
  constexpr int CONVSM = PB + BB + CIN * 8 + CB * 32;
  constexpr int SMSZ = CONVSM > 52288 ? CONVSM : 52288;
  __shared__ __align__(16) char sm[SMSZ];
  const int tid = threadIdx.x;
  if (blockIdx.x < NLB) { LSTM_PASS(blockIdx.x); return; }
  const int bidc = blockIdx.x - NLB;

  unsigned short* patch = (unsigned short*)sm;
  unsigned short* Bsm = (unsigned short*)(sm + PB);
  float* ssl = (float*)(sm + PB + BB);
  float* swsum = (float*)(sm + PB + BB + CIN * 8);
  float* swsq = swsum + 4 * CB;

  const int n = bidc / ((TPR * TPR) * NS);
  const int rem = bidc % ((TPR * TPR) * NS);
  const int tile = rem / NS;
  const int split = rem % NS;
  const int TR0 = (tile / TPR) * 8, TC0 = (tile % TPR) * 8;
  const int oc0 = split * CB;

  for (int i = tid; i < CIN * 2; i += TPB) ssl[i] = ssx[i];
  __syncthreads();

  for (int e = tid; e < 289 * (CIN / 8); e += TPB) {
    int icg = e % (CIN / 8), pix = e / (CIN / 8);
    int row = pix / 17, col = pix % 17;
    int ir = 2 * TR0 - 1 + row, jc = 2 * TC0 - 1 + col;
    uint4 o = {0u, 0u, 0u, 0u};
    if ((unsigned)ir < (unsigned)HIN && (unsigned)jc < (unsigned)HIN) {
      uint4 v = *(const uint4*)&inb[(((size_t)n * HIN + ir) * HIN + jc) * CIN + icg * 8];
      unsigned int d[4] = {v.x, v.y, v.z, v.w};
      unsigned int* op = (unsigned int*)&o;
#pragma unroll
      for (int t = 0; t < 4; ++t) {
        int c = icg * 8 + 2 * t;
        float a = fmaxf(fmaf(bf2f((unsigned short)(d[t] & 0xffff)), ssl[2 * c], ssl[2 * c + 1]), 0.f);
        float b = fmaxf(fmaf(bf2f((unsigned short)(d[t] >> 16)), ssl[2 * c + 2], ssl[2 * c + 3]), 0.f);
        op[t] = (unsigned int)f2bf(a) | ((unsigned int)f2bf(b) << 16);
      }
    }
    *(uint4*)&patch[pix * CINP + icg * 8] = o;
  }
  for (int e = tid; e < CB * (KPAD / 8); e += TPB) {
    int oc = e / (KPAD / 8), k8i = e % (KPAD / 8);
    uint4 v = {0u, 0u, 0u, 0u};
    if (k8i * 8 < K) v = *(const uint4*)&wT[(size_t)(oc0 + oc) * K + k8i * 8];
    *(uint4*)&Bsm[oc * BS + k8i * 8] = v;
  }
  __syncthreads();

  const int wave = tid >> 6, lane = tid & 63;
  const int fr = lane & 15, kg = lane >> 4;
  const int p = wave * 16 + fr;
  const int pr = p >> 3, pc = p & 7;
  f32x4 acc[NT];
#pragma unroll
  for (int j = 0; j < NT; ++j) acc[j] = {0.f, 0.f, 0.f, 0.f};

#pragma unroll
  for (int ch = 0; ch < NCH; ++ch) {
    int k8 = ch * 4 + kg;
    int tap = k8 >> ICG_SH, icg = k8 & ((1 << ICG_SH) - 1);
    int ki = (tap * 11) >> 5;
    int kj = tap - 3 * ki;
    int addr = ((2 * pr + ki) * 17 + (2 * pc + kj)) * CINP + icg * 8;
    if (tap >= 9) addr = 0;
    bf16x8 af = lda_bf8(&patch[addr]);
#pragma unroll
    for (int j = 0; j < NT; ++j) {
      bf16x8 bfr = lda_bf8(&Bsm[(j * 16 + fr) * BS + ch * 32 + kg * 8]);
      acc[j] = __builtin_amdgcn_mfma_f32_16x16x32_bf16(af, bfr, acc[j], 0, 0, 0);
    }
  }
  const int rg = lane >> 4;
#pragma unroll
  for (int j = 0; j < NT; ++j) {
    int oc = oc0 + j * 16 + fr;
    float bb = bias[oc];
    float s1 = 0.f, q1 = 0.f;
#pragma unroll
    for (int r = 0; r < 4; ++r) {
      int pp = wave * 16 + rg * 4 + r;
      int orow = TR0 + (pp >> 3), ocol = TC0 + (pp & 7);
      float v = acc[j][r] + bb;
      s1 += v; q1 = fmaf(v, v, q1);
      out[(((size_t)n * HOUT + orow) * HOUT + ocol) * COUT_TOT + oc] = f2bf(v);
    }
    s1 += __shfl_xor(s1, 16); q1 += __shfl_xor(q1, 16);
    s1 += __shfl_xor(s1, 32); q1 += __shfl_xor(q1, 32);
    if (lane < 16) { swsum[wave * CB + j * 16 + fr] = s1; swsq[wave * CB + j * 16 + fr] = q1; }
  }
  __syncthreads();
  if (tid < CB) {
    float s = swsum[tid] + swsum[CB + tid] + swsum[2 * CB + tid] + swsum[3 * CB + tid];
    float q = swsq[tid] + swsq[CB + tid] + swsq[2 * CB + tid] + swsq[3 * CB + tid];
    part[(size_t)bidc * CB * 2 + tid * 2] = s;
    part[(size_t)bidc * CB * 2 + tid * 2 + 1] = q;
  }
}

// ================= k_fc1: fc1 tiles (+ final LSTM seg) =================
__global__ __launch_bounds__(TPB, 2) void k_fc1(
    const unsigned short* __restrict__ A, const unsigned short* __restrict__ W,
    const float* __restrict__ ssx, const float* __restrict__ bias, float* __restrict__ out,
    LSTM_ARGS) {
  __shared__ __align__(16) char sm[52288];
  const int tid = threadIdx.x;
  if (blockIdx.x < NLB) { LSTM_PASS(blockIdx.x); return; }
  const int cid = blockIdx.x - NLB;
  const int bm = (cid >> 3) * 64, bn = (cid & 7) * 64;

  unsigned short (*As)[64] = (unsigned short (*)[64])sm;
  unsigned short (*Bs)[64] = (unsigned short (*)[64])(sm + 8192);
  float* ssl = (float*)(sm + 16384);
  const int lane = tid & 63, wave = tid >> 6;
  const int wr = (wave >> 1) * 32, wc = (wave & 1) * 32;
  f32x4 acc00 = {0.f, 0.f, 0.f, 0.f}, acc01 = acc00, acc10 = acc00, acc11 = acc00;
  const int r0 = tid >> 3, c0 = tid & 7;
  const int fr = lane & 15, kg = lane >> 4;
  for (int i = tid; i < 256; i += TPB) ssl[i] = ssx[i];
  __syncthreads();
  for (int kt = 0; kt < 128; ++kt) {
    const int kb = kt * 64;
    uint4 av0 = *(const uint4*)&A[(size_t)(bm + r0) * 8192 + kb + c0 * 8];
    uint4 av1 = *(const uint4*)&A[(size_t)(bm + r0 + 32) * 8192 + kb + c0 * 8];
    uint4 bv0 = *(const uint4*)&W[(size_t)(bn + r0) * 8192 + kb + c0 * 8];
    uint4 bv1 = *(const uint4*)&W[(size_t)(bn + r0 + 32) * 8192 + kb + c0 * 8];
    const float* sst = &ssl[2 * ((kb + c0 * 8) & 127)];
    __syncthreads();
    av0 = bnpack(av0, sst);
    av1 = bnpack(av1, sst);
    *(uint4*)&As[r0][(c0 ^ (r0 & 7)) * 8] = av0;
    *(uint4*)&As[r0 + 32][(c0 ^ (r0 & 7)) * 8] = av1;
    *(uint4*)&Bs[r0][(c0 ^ (r0 & 7)) * 8] = bv0;
    *(uint4*)&Bs[r0 + 32][(c0 ^ (r0 & 7)) * 8] = bv1;
    __syncthreads();
#pragma unroll
    for (int ks = 0; ks < 2; ++ks) {
      int ch = ks * 4 + kg;
      int ra0 = wr + fr, ra1 = wr + 16 + fr;
      int rb0 = wc + fr, rb1 = wc + 16 + fr;
      bf16x8 a_0 = lda_bf8(&As[ra0][(ch ^ (ra0 & 7)) * 8]);
      bf16x8 a_1 = lda_bf8(&As[ra1][(ch ^ (ra1 & 7)) * 8]);
      bf16x8 b_0 = lda_bf8(&Bs[rb0][(ch ^ (rb0 & 7)) * 8]);
      bf16x8 b_1 = lda_bf8(&Bs[rb1][(ch ^ (rb1 & 7)) * 8]);
      acc00 = __builtin_amdgcn_mfma_f32_16x16x32_bf16(a_0, b_0, acc00, 0, 0, 0);
      acc01 = __builtin_amdgcn_mfma_f32_16x16x32_bf16(a_0, b_1, acc01, 0, 0, 0);
      acc10 = __builtin_amdgcn_mfma_f32_16x16x32_bf16(a_1, b_0, acc10, 0, 0, 0);
      acc11 = __builtin_amdgcn_mfma_f32_16x16x32_bf16(a_1, b_1, acc11, 0, 0, 0);
    }
  }
  const int rg = lane >> 4;
  int n0 = bn + wc + fr, n1 = n0 + 16;
  float bi0 = bias[n0], bi1 = bias[n1];
#pragma unroll
  for (int r = 0; r < 4; ++r) {
    int m0 = bm + wr + rg * 4 + r, m1 = m0 + 16;
    out[m0 * 512 + n0] = fmaxf(acc00[r] + bi0, 0.f);
    out[m0 * 512 + n1] = fmaxf(acc01[r] + bi1, 0.f);
    out[m1 * 512 + n0] = fmaxf(acc10[r] + bi0, 0.f);
    out[m1 * 512 + n1] = fmaxf(acc11[r] + bi1, 0.f);
  }
}

// ---------- final BN reduce over per-block partials (r11) ----------
__global__ __launch_bounds__(TPB) void stats_final3(const float* __restrict__ part,
    const float* __restrict__ gamma, const float* __restrict__ beta,
    float* __restrict__ ss, float inv_count, int COUT_BLK, int NSPLIT, int NBID) {
  const int c = blockIdx.x, tid = threadIdx.x;
  const int split = c / COUT_BLK, loc = c % COUT_BLK;
  const int NG = NBID / NSPLIT;
  float s = 0.f, q = 0.f;
  for (int g = tid; g < NG; g += TPB) {
    size_t b = (size_t)g * NSPLIT + split;
    s += part[b * COUT_BLK * 2 + loc * 2];
    q += part[b * COUT_BLK * 2 + loc * 2 + 1];
  }
  __shared__ float rs[TPB], rq[TPB];
  rs[tid] = s; rq[tid] = q;
  __syncthreads();
  for (int off = TPB / 2; off > 0; off >>= 1) {
    if (tid < off) { rs[tid] += rs[tid + off]; rq[tid] += rq[tid + off]; }
    __syncthreads();
  }
  if (tid == 0) {
    float mean = rs[0] * inv_count;
    float var  = rq[0] * inv_count - mean * mean;
    float rstd = rsqrtf(var + 1e-5f);
    float scl  = gamma[c] * rstd;
    ss[2 * c] = scl;
    ss[2 * c + 1] = beta[c] - mean * scl;
  }
}

// ---------- prep kernels (r11) ----------
__global__ __launch_bounds__(TPB) void prep_wt(
    const float* __restrict__ w1, const float* __restrict__ w2,
    const float* __restrict__ w3, const float* __restrict__ w4,
    unsigned short* __restrict__ wt1, unsigned short* __restrict__ wt2,
    unsigned short* __restrict__ wt3, unsigned short* __restrict__ wt4) {
  int i = blockIdx.x * TPB + threadIdx.x;
  if (i < 1536) {
    int oc = i / 96, k = i % 96;
    int tap = k >> 3, ic = k & 7;
    float v = (tap < 9 && ic < 3) ? w1[(oc * 3 + ic) * 9 + tap] : 0.f;
    wt1[i] = f2bf(v);
  } else if (i < 6144) {
    int j = i - 1536;
    int oc = j / 144, k = j % 144;
    wt2[j] = f2bf(w2[(oc * 16 + (k & 15)) * 9 + (k >> 4)]);
  } else if (i < 24576) {
    int j = i - 6144;
    int oc = j / 288, k = j % 288;
    wt3[j] = f2bf(w3[(oc * 32 + (k & 31)) * 9 + (k >> 5)]);
  } else if (i < 98304) {
    int j = i - 24576;
    int oc = j / 576, k = j % 576;
    wt4[j] = f2bf(w4[(oc * 64 + (k & 63)) * 9 + (k >> 6)]);
  }
}

__global__ __launch_bounds__(TPB) void permute_fw1(const float* __restrict__ in,
    unsigned short* __restrict__ out) {
  __shared__ unsigned short l[128 * 66];
  int n = blockIdx.x;
  for (int e = threadIdx.x; e < 8192; e += TPB) {
    int c = e >> 6, pix = e & 63;
    l[c * 66 + pix] = f2bf(in[(size_t)n * 8192 + e]);
  }
  __syncthreads();
  for (int e = threadIdx.x; e < 8192; e += TPB) {
    int pix = e >> 7, c = e & 127;
    out[(size_t)n * 8192 + e] = l[c * 66 + pix];
  }
}

// ---------- small GEMM via MFMA (r11) ----------
__global__ __launch_bounds__(TPB, 2) void gemm_m64(
    const float* __restrict__ A, const float* __restrict__ W,
    const float* __restrict__ bias, float* __restrict__ out,
    int N, int K, int relu, int ldo, int coff) {
  __shared__ unsigned short As[64 * 40];
  __shared__ unsigned short Bs[64 * 40];
  const int tid = threadIdx.x, lane = tid & 63, wave = tid >> 6;
  const int wr = (wave >> 1) * 32, wc = (wave & 1) * 32;
  const int bm = blockIdx.y * 64, bn = blockIdx.x * 64;
  const int fr = lane & 15, kg = lane >> 4;
  const int sr = tid >> 2, sc = (tid & 3) * 8;
  f32x4 a00 = {0.f, 0.f, 0.f, 0.f}, a01 = a00, a10 = a00, a11 = a00;
  int nch = (K + 31) >> 5;
  for (int ch = 0; ch < nch; ++ch) {
    int kb = ch * 32;
    __syncthreads();
    {
      unsigned short tmp[8];
#pragma unroll
      for (int j = 0; j < 8; ++j) {
        int k = kb + sc + j;
        tmp[j] = (k < K) ? f2bf(A[(size_t)(bm + sr) * K + k]) : (unsigned short)0;
      }
      *(uint4*)&As[sr * 40 + sc] = *(const uint4*)tmp;
      int wrow = bn + sr;
#pragma unroll
      for (int j = 0; j < 8; ++j) {
        int k = kb + sc + j;
        tmp[j] = (wrow < N && k < K) ? f2bf(W[(size_t)wrow * K + k]) : (unsigned short)0;
      }
      *(uint4*)&Bs[sr * 40 + sc] = *(const uint4*)tmp;
    }
    __syncthreads();
    bf16x8 af0 = lda_bf8(&As[(wr + fr) * 40 + kg * 8]);
    bf16x8 af1 = lda_bf8(&As[(wr + 16 + fr) * 40 + kg * 8]);
    bf16x8 bf0 = lda_bf8(&Bs[(wc + fr) * 40 + kg * 8]);
    bf16x8 bf1 = lda_bf8(&Bs[(wc + 16 + fr) * 40 + kg * 8]);
    a00 = __builtin_amdgcn_mfma_f32_16x16x32_bf16(af0, bf0, a00, 0, 0, 0);
    a01 = __builtin_amdgcn_mfma_f32_16x16x32_bf16(af0, bf1, a01, 0, 0, 0);
    a10 = __builtin_amdgcn_mfma_f32_16x16x32_bf16(af1, bf0, a10, 0, 0, 0);
    a11 = __builtin_amdgcn_mfma_f32_16x16x32_bf16(af1, bf1, a11, 0, 0, 0);
  }
  const int rg = lane >> 4;
  int n0 = bn + wc + fr, n1 = n0 + 16;
  float bi0 = (n0 < N) ? bias[n0] : 0.f;
  float bi1 = (n1 < N) ? bias[n1] : 0.f;
#pragma unroll
  for (int r = 0; r < 4; ++r) {
    int m0 = bm + wr + rg * 4 + r, m1 = m0 + 16;
    if (n0 < N) {
      float v = a00[r] + bi0; out[(size_t)m0 * ldo + coff + n0] = relu ? fmaxf(v, 0.f) : v;
      v = a10[r] + bi0;       out[(size_t)m1 * ldo + coff + n0] = relu ? fmaxf(v, 0.f) : v;
    }
    if (n1 < N) {
      float v = a01[r] + bi1; out[(size_t)m0 * ldo + coff + n1] = relu ? fmaxf(v, 0.f) : v;
      v = a11[r] + bi1;       out[(size_t)m1 * ldo + coff + n1] = relu ? fmaxf(v, 0.f) : v;
    }
  }
}

// ---------- fused condition encoder (r11) ----------
__global__ __launch_bounds__(TPB) void cond_enc(
    const float* __restrict__ cond, const float* __restrict__ steps,
    const float* __restrict__ ew1, const float* __restrict__ eb1,
    const float* __restrict__ ew2, const float* __restrict__ eb2,
    float* __restrict__ comb) {
  __shared__ float w1s[128][8];
  __shared__ float w2s[64][132];
  __shared__ float hbuf[64][132];
  const int tid = threadIdx.x;
  const int row0 = blockIdx.x * 64;
  for (int e = tid; e < 128 * 8; e += TPB) {
    int k = e >> 3, t = e & 7;
    w1s[k][t] = (t < 6) ? ew1[k * 6 + t] : (t == 6 ? eb1[k] : 0.f);
  }
  for (int e = tid; e < 64 * 128; e += TPB) {
    int j = e >> 7, k = e & 127;
    w2s[j][k] = ew2[j * 128 + k];
  }
  __syncthreads();
  {
    int row = tid >> 2, ks = tid & 3;
    int n = row0 + row;
    int b = n >> 6, s = n & 63;
    float e0 = cond[b * 5], e1 = cond[b * 5 + 1], e2 = cond[b * 5 + 2];
    float e3 = cond[b * 5 + 3], e4 = cond[b * 5 + 4];
    float e5 = steps[b * 64 + s];
    for (int k = ks * 32; k < ks * 32 + 32; ++k) {
      float a = fmaf(w1s[k][0], e0, fmaf(w1s[k][1], e1, fmaf(w1s[k][2], e2,
                fmaf(w1s[k][3], e3, fmaf(w1s[k][4], e4, fmaf(w1s[k][5], e5, w1s[k][6]))))));
      hbuf[row][k] = fmaxf(a, 0.f);
    }
  }
  __syncthreads();
  {
    int row = tid >> 2, js = tid & 3;
    int n = row0 + row;
    for (int j = js * 16; j < js * 16 + 16; ++j) {
      float a = eb2[j];
#pragma unroll 8
      for (int k = 0; k < 128; ++k) a = fmaf(w2s[j][k], hbuf[row][k], a);
      comb[(size_t)n * 576 + 512 + j] = a;
    }
  }
}

// ---------- launcher ----------
extern "C" void kernel_launch(void* const* d_in, const int* in_sizes, int n_in,
                              void* d_out, int out_size, void* d_ws, size_t ws_size,
                              hipStream_t stream) {
  const float* fmap  = (const float*)d_in[0];
  const float* cond  = (const float*)d_in[1];
  const float* iseq  = (const float*)d_in[2];
  const float* steps = (const float*)d_in[3];
  const float* cw1 = (const float*)d_in[4];  const float* cb1 = (const float*)d_in[5];
  const float* g1  = (const float*)d_in[6];  const float* be1 = (const float*)d_in[7];
  const float* cw2 = (const float*)d_in[8];  const float* cb2 = (const float*)d_in[9];
  const float* g2  = (const float*)d_in[10]; const float* be2 = (const float*)d_in[11];
  const float* cw3 = (const float*)d_in[12]; const float* cb3 = (const float*)d_in[13];
  const float* g3  = (const float*)d_in[14]; const float* be3 = (const float*)d_in[15];
  const float* cw4 = (const float*)d_in[16]; const float* cb4 = (const float*)d_in[17];
  const float* g4  = (const float*)d_in[18]; const float* be4 = (const float*)d_in[19];
  const float* fw1 = (const float*)d_in[20]; const float* fb1 = (const float*)d_in[21];
  const float* fw2 = (const float*)d_in[22]; const float* fb2 = (const float*)d_in[23];
  const float* ew1 = (const float*)d_in[24]; const float* eb1 = (const float*)d_in[25];
  const float* ew2 = (const float*)d_in[26]; const float* eb2 = (const float*)d_in[27];
  const float* mw  = (const float*)d_in[28]; const float* mb  = (const float*)d_in[29];
  const float* w_ih0 = (const float*)d_in[30]; const float* w_hh0 = (const float*)d_in[31];
  const float* b_ih0 = (const float*)d_in[32]; const float* b_hh0 = (const float*)d_in[33];
  const float* w_ih1 = (const float*)d_in[34]; const float* w_hh1 = (const float*)d_in[35];
  const float* b_ih1 = (const float*)d_in[36]; const float* b_hh1 = (const float*)d_in[37];
  const float* xw1 = (const float*)d_in[38]; const float* xb1 = (const float*)d_in[39];
  const float* xw2 = (const float*)d_in[40]; const float* xb2 = (const float*)d_in[41];
  const float* ow  = (const float*)d_in[42]; const float* ob  = (const float*)d_in[43];

  float* ws = (float*)d_ws;
  unsigned short* y1bf  = (unsigned short*)ws;
  unsigned short* y2bf  = (unsigned short*)(ws + 16777216);
  unsigned short* y3bf  = (unsigned short*)(ws + 25165824);
  unsigned short* y4pre = (unsigned short*)(ws + 29360128);
  unsigned short* fw1bf = (unsigned short*)(ws + 33554432);
  size_t base = 35651584;
  float* part  = ws + base; base += 524288;
  float* ss1   = ws + base; base += 32;
  float* ss2   = ws + base; base += 64;
  float* ss3   = ws + base; base += 128;
  float* ss4   = ws + base; base += 256;
  float* f1    = ws + base; base += 262144;
  u64*   h0x   = (u64*)(ws + base); base += 131072;
  u64*   h1x   = (u64*)(ws + base); base += 131072;
  float* comb  = ws + base; base += 294912;
  float* cx1   = ws + base; base += 65536;
  float* cx2   = ws + base; base += 32768;
  unsigned short* wt1 = (unsigned short*)(ws + base); base += 768;
  unsigned short* wt2 = (unsigned short*)(ws + base); base += 2304;
  unsigned short* wt3 = (unsigned short*)(ws + base); base += 9216;
  unsigned short* wt4 = (unsigned short*)(ws + base); base += 36864;
  float* xzg = ws + base; base += 524288;   // 64 blocks x 8192
  float* cst = ws + base; base += 4096;

  // --- prep ---
  prep_wt<<<384, TPB, 0, stream>>>(cw1, cw2, cw3, cw4, wt1, wt2, wt3, wt4);
  permute_fw1<<<512, TPB, 0, stream>>>(fw1, fw1bf);
  hipMemsetAsync(h0x, 0, 2 * 64 * 1024 * sizeof(u64), stream);

  // --- overlapped conv chain + segmented LSTM (phases [0,24,38,45,52,65]) ---
  k_conv1<<<NLB + 4096, TPB, 0, stream>>>(fmap, iseq, wt1, cb1, y1bf, part,
      iseq, mw, mb, w_ih0, w_hh0, b_ih0, b_hh0, w_ih1, w_hh1, b_ih1, b_hh1,
      h0x, h1x, comb, xzg, cst, 0, 24, 1);
  stats_final3<<<16, TPB, 0, stream>>>(part, g1, be1, ss1, 1.f / 2097152.f, 16, 1, 4096);
  k_conv<16, 32, 1, 64, 32><<<NLB + 8192, TPB, 0, stream>>>(y1bf, ss1, wt2, cb2, y2bf, part,
      iseq, mw, mb, w_ih0, w_hh0, b_ih0, b_hh0, w_ih1, w_hh1, b_ih1, b_hh1,
      h0x, h1x, comb, xzg, cst, 24, 38, 0);
  stats_final3<<<32, TPB, 0, stream>>>(part, g2, be2, ss2, 1.f / 524288.f, 32, 1, 8192);
  k_conv<32, 64, 1, 32, 16><<<NLB + 2048, TPB, 0, stream>>>(y2bf, ss2, wt3, cb3, y3bf, part,
      iseq, mw, mb, w_ih0, w_hh0, b_ih0, b_hh0, w_ih1, w_hh1, b_ih1, b_hh1,
      h0x, h1x, comb, xzg, cst, 38, 45, 0);
  stats_final3<<<64, TPB, 0, stream>>>(part, g3, be3, ss3, 1.f / 131072.f, 64, 1, 2048);
  k_conv<64, 32, 4, 16, 8><<<NLB + 2048, TPB, 0, stream>>>(y3bf, ss3, wt4, cb4, y4pre, part,
      iseq, mw, mb, w_ih0, w_hh0, b_ih0, b_hh0, w_ih1, w_hh1, b_ih1, b_hh1,
      h0x, h1x, comb, xzg, cst, 45, 52, 0);
  stats_final3<<<128, TPB, 0, stream>>>(part, g4, be4, ss4, 1.f / 32768.f, 32, 4, 2048);
  k_fc1<<<NLB + 64, TPB, 0, stream>>>(y4pre, fw1bf, ss4, fb1, f1,
      iseq, mw, mb, w_ih0, w_hh0, b_ih0, b_hh0, w_ih1, w_hh1, b_ih1, b_hh1,
      h0x, h1x, comb, xzg, cst, 52, 65, 0);

  // --- map-feature MLP tail + condition encoder ---
  gemm_m64<<<dim3(4, 8), TPB, 0, stream>>>(f1, fw2, fb2, comb, 256, 512, 0, 576, 256);
  cond_enc<<<8, TPB, 0, stream>>>(cond, steps, ew1, eb1, ew2, eb2, comb);

  // --- head ---
  gemm_m64<<<dim3(2, 8), TPB, 0, stream>>>(comb, xw1, xb1, cx1, 128, 576, 1, 128, 0);
  gemm_m64<<<dim3(1, 8), TPB, 0, stream>>>(cx1, xw2, xb2, cx2, 64, 128, 1, 64, 0);
  gemm_m64<<<dim3(1, 8), TPB, 0, stream>>>(cx2, ow, ob, (float*)d_out, 2, 64, 0, 2, 0);
}